// Round 1
// baseline (134.722 us; speedup 1.0000x reference)
//
#include <hip/hip_runtime.h>

static constexpr int B = 128;
static constexpr int G = 64;
static constexpr int P = 8732;
static constexpr float EPS = 1e-5f;
static constexpr float IOU_THR = 0.5f;

// Bitwise-numpy-identical IoU: no contraction, IEEE div, numpy association order:
//   lt=max, rb=min, hw=max(rb-lt,0), ov=hw0*hw1, den=((ga+pa)-ov)+eps, ov/den
__device__ __forceinline__ float iou_exact(
    float gx1, float gy1, float gx2, float gy2, float ga,
    float px1, float py1, float px2, float py2, float pa)
{
    float ltx = fmaxf(gx1, px1), lty = fmaxf(gy1, py1);
    float rbx = fminf(gx2, px2), rby = fminf(gy2, py2);
    float ow  = fmaxf(__fsub_rn(rbx, ltx), 0.0f);
    float oh  = fmaxf(__fsub_rn(rby, lty), 0.0f);
    float ov  = __fmul_rn(ow, oh);
    float den = __fadd_rn(__fsub_rn(__fadd_rn(ga, pa), ov), EPS);
    return __fdiv_rn(ov, den);
}

// Kernel 1: one wave per (b,g) -> argmax over p of iou, first-p tie-break.
__global__ __launch_bounds__(256) void k_best_prior(
    const float* __restrict__ gt_boxes,   // [B,G,4] corner
    const float* __restrict__ priors,     // [P,4] center
    int* __restrict__ bppt)               // [B,G]
{
    const int wid  = (blockIdx.x * 256 + threadIdx.x) >> 6;   // 0..B*G-1
    const int lane = threadIdx.x & 63;
    const float4 gb = *(const float4*)(gt_boxes + (size_t)wid * 4);
    const float ga = __fmul_rn(fmaxf(__fsub_rn(gb.z, gb.x), 0.0f),
                               fmaxf(__fsub_rn(gb.w, gb.y), 0.0f));
    unsigned long long best = 0ull;
    for (int p = lane; p < P; p += 64) {
        float4 pr = *(const float4*)(priors + (size_t)p * 4);
        float hw = __fmul_rn(pr.z, 0.5f), hh = __fmul_rn(pr.w, 0.5f);
        float px1 = __fsub_rn(pr.x, hw), py1 = __fsub_rn(pr.y, hh);
        float px2 = __fadd_rn(pr.x, hw), py2 = __fadd_rn(pr.y, hh);
        float pa  = __fmul_rn(fmaxf(__fsub_rn(px2, px1), 0.0f),
                              fmaxf(__fsub_rn(py2, py1), 0.0f));
        float iou = iou_exact(gb.x, gb.y, gb.z, gb.w, ga, px1, py1, px2, py2, pa);
        // higher iou wins; equal iou -> smaller p wins (numpy argmax first-index)
        unsigned long long key =
            ((unsigned long long)__float_as_uint(iou) << 32) |
            (unsigned long long)(0xFFFFFFFFu - (unsigned)p);
        best = key > best ? key : best;
    }
#pragma unroll
    for (int off = 32; off > 0; off >>= 1) {
        unsigned long long o = __shfl_xor(best, off, 64);
        best = o > best ? o : best;
    }
    if (lane == 0)
        bppt[wid] = (int)(0xFFFFFFFFu - (unsigned)(best & 0xFFFFFFFFull));
}

// Kernel 2: one thread per (b,p): max/argmax over g, force-assign, encode.
__global__ __launch_bounds__(256) void k_assign(
    const float* __restrict__ gt_boxes,   // [B,G,4]
    const int*   __restrict__ gt_labels,  // [B,G]
    const float* __restrict__ priors,     // [P,4] center
    const int*   __restrict__ bppt,       // [B,G]
    float* __restrict__ out_loc,          // [B,P,4]
    float* __restrict__ out_lab)          // [B,P] (written as float)
{
    __shared__ float4 s_gt[G];
    __shared__ float  s_ga[G];
    __shared__ int    s_bp[G];
    __shared__ int    s_lab[G];

    const int b = blockIdx.y;
    const int t = threadIdx.x;
    const int p = blockIdx.x * 256 + t;

    if (t < G) {
        float4 gb = *(const float4*)(gt_boxes + (size_t)(b * G + t) * 4);
        s_gt[t]  = gb;
        s_ga[t]  = __fmul_rn(fmaxf(__fsub_rn(gb.z, gb.x), 0.0f),
                             fmaxf(__fsub_rn(gb.w, gb.y), 0.0f));
        s_bp[t]  = bppt[b * G + t];
        s_lab[t] = gt_labels[b * G + t];
    }
    __syncthreads();
    if (p >= P) return;

    float4 pr = *(const float4*)(priors + (size_t)p * 4);
    float hw = __fmul_rn(pr.z, 0.5f), hh = __fmul_rn(pr.w, 0.5f);
    float px1 = __fsub_rn(pr.x, hw), py1 = __fsub_rn(pr.y, hh);
    float px2 = __fadd_rn(pr.x, hw), py2 = __fadd_rn(pr.y, hh);
    float pa  = __fmul_rn(fmaxf(__fsub_rn(px2, px1), 0.0f),
                          fmaxf(__fsub_rn(py2, py1), 0.0f));

    float bestIou = -1.0f;
    int   bestG   = 0;
    for (int g = 0; g < G; ++g) {
        float4 gb = s_gt[g];
        float iou = iou_exact(gb.x, gb.y, gb.z, gb.w, s_ga[g],
                              px1, py1, px2, py2, pa);
        if (iou > bestIou) { bestIou = iou; bestG = g; }   // first-g tie-break
    }
    // Force-assign: scatter duplicates resolve last-index-wins (numpy).
    for (int g = G - 1; g >= 0; --g) {
        if (s_bp[g] == p) { bestG = g; bestIou = 2.0f; break; }
    }

    int lab = (bestIou < IOU_THR) ? 0 : s_lab[bestG];

    float4 gb = s_gt[bestG];
    float cx = (gb.x + gb.z) * 0.5f;
    float cy = (gb.y + gb.w) * 0.5f;
    float w  = gb.z - gb.x;
    float h  = gb.w - gb.y;
    float4 loc;
    loc.x = (cx - pr.x) / (pr.z * 0.1f);
    loc.y = (cy - pr.y) / (pr.w * 0.1f);
    loc.z = logf(w / pr.z) / 0.2f;
    loc.w = logf(h / pr.w) / 0.2f;

    *(float4*)(out_loc + (size_t)(b * P + p) * 4) = loc;
    out_lab[b * P + p] = (float)lab;
}

extern "C" void kernel_launch(void* const* d_in, const int* in_sizes, int n_in,
                              void* d_out, int out_size, void* d_ws, size_t ws_size,
                              hipStream_t stream)
{
    const float* gt_boxes  = (const float*)d_in[0];
    const int*   gt_labels = (const int*)d_in[1];
    const float* priors    = (const float*)d_in[2];

    float* out_loc = (float*)d_out;                       // B*P*4 floats
    float* out_lab = out_loc + (size_t)B * P * 4;         // B*P floats
    int*   bppt    = (int*)d_ws;                          // B*G ints (32 KB)

    // K1: B*G = 8192 waves, 4 waves/block -> 2048 blocks
    k_best_prior<<<dim3((B * G) / 4), 256, 0, stream>>>(gt_boxes, priors, bppt);

    // K2: one thread per (b,p)
    k_assign<<<dim3((P + 255) / 256, B), 256, 0, stream>>>(
        gt_boxes, gt_labels, priors, bppt, out_loc, out_lab);
}

// Round 2
// 83.174 us; speedup vs baseline: 1.6198x; 1.6198x over previous
//
#include <hip/hip_runtime.h>

static constexpr int B = 128;
static constexpr int G = 64;
static constexpr int P = 8732;
static constexpr float EPS = 1e-5f;
static constexpr float IOU_THR = 0.5f;

// Bitwise-numpy-identical IoU: no contraction, IEEE div, numpy association order:
//   lt=max, rb=min, hw=max(rb-lt,0), ov=hw0*hw1, den=((ga+pa)-ov)+eps, ov/den
__device__ __forceinline__ float iou_exact(
    float gx1, float gy1, float gx2, float gy2, float ga,
    float px1, float py1, float px2, float py2, float pa)
{
    float ltx = fmaxf(gx1, px1), lty = fmaxf(gy1, py1);
    float rbx = fminf(gx2, px2), rby = fminf(gy2, py2);
    float ow  = fmaxf(__fsub_rn(rbx, ltx), 0.0f);
    float oh  = fmaxf(__fsub_rn(rby, lty), 0.0f);
    float ov  = __fmul_rn(ow, oh);
    float den = __fadd_rn(__fsub_rn(__fadd_rn(ga, pa), ov), EPS);
    return __fdiv_rn(ov, den);
}

__device__ __forceinline__ void encode_store(
    float* out_loc, float* out_lab, int b, int p,
    float4 gb, float4 pr, int lab)
{
    float cx = (gb.x + gb.z) * 0.5f;
    float cy = (gb.y + gb.w) * 0.5f;
    float w  = gb.z - gb.x;
    float h  = gb.w - gb.y;
    float4 loc;
    loc.x = (cx - pr.x) / (pr.z * 0.1f);
    loc.y = (cy - pr.y) / (pr.w * 0.1f);
    loc.z = logf(w / pr.z) / 0.2f;
    loc.w = logf(h / pr.w) / 0.2f;
    *(float4*)(out_loc + (size_t)(b * P + p) * 4) = loc;
    out_lab[(size_t)b * P + p] = (float)lab;
}

// Zero the packed per-(b,g) reduction array each call (atomicMax is monotone).
__global__ __launch_bounds__(256) void k_zero(unsigned long long* __restrict__ packed)
{
    int i = blockIdx.x * 256 + threadIdx.x;
    if (i < B * G) packed[i] = 0ull;
}

// Fused: one pass over all B*G*P IoUs.
//  - per-(b,p) argmax over g  -> provisional labels/locations written directly
//  - per-(b,g) argmax over p  -> packed (iou<<32)|(~p) via LDS + global atomicMax
__global__ __launch_bounds__(256) void k_fused(
    const float* __restrict__ gt_boxes,   // [B,G,4] corner
    const int*   __restrict__ gt_labels,  // [B,G]
    const float* __restrict__ priors,     // [P,4] center
    unsigned long long* __restrict__ packed,  // [B,G]
    float* __restrict__ out_loc,          // [B,P,4]
    float* __restrict__ out_lab)          // [B,P]
{
    __shared__ float4 s_gt[G];
    __shared__ float  s_ga[G];
    __shared__ int    s_lab[G];
    __shared__ float  s_iou[256][33];     // padded: bank = (33r+g)%32 = (r+g)%32
    __shared__ unsigned long long s_red[G];

    const int b = blockIdx.y;
    const int t = threadIdx.x;
    const int pbase = blockIdx.x * 256;
    const int p = pbase + t;
    const bool valid = p < P;

    if (t < G) {
        float4 gb = *(const float4*)(gt_boxes + (size_t)(b * G + t) * 4);
        s_gt[t]  = gb;
        s_ga[t]  = __fmul_rn(fmaxf(__fsub_rn(gb.z, gb.x), 0.0f),
                             fmaxf(__fsub_rn(gb.w, gb.y), 0.0f));
        s_lab[t] = gt_labels[b * G + t];
        s_red[t] = 0ull;
    }
    __syncthreads();

    float4 pr = make_float4(0.f, 0.f, 1.f, 1.f);
    float px1 = 0.f, py1 = 0.f, px2 = 0.f, py2 = 0.f, pa = 0.f;
    if (valid) {
        pr = *(const float4*)(priors + (size_t)p * 4);
        float hw = __fmul_rn(pr.z, 0.5f), hh = __fmul_rn(pr.w, 0.5f);
        px1 = __fsub_rn(pr.x, hw); py1 = __fsub_rn(pr.y, hh);
        px2 = __fadd_rn(pr.x, hw); py2 = __fadd_rn(pr.y, hh);
        pa  = __fmul_rn(fmaxf(__fsub_rn(px2, px1), 0.0f),
                        fmaxf(__fsub_rn(py2, py1), 0.0f));
    }

    float bestIou = -1.0f;
    int   bestG   = 0;

    for (int half = 0; half < 2; ++half) {
        const int gbase = half * 32;
#pragma unroll 8
        for (int gi = 0; gi < 32; ++gi) {
            int g = gbase + gi;
            float4 gb = s_gt[g];
            float iou = iou_exact(gb.x, gb.y, gb.z, gb.w, s_ga[g],
                                  px1, py1, px2, py2, pa);
            iou = valid ? iou : -1.0f;
            s_iou[t][gi] = iou;
            if (iou > bestIou) { bestIou = iou; bestG = g; }  // first-g tie-break
        }
        __syncthreads();

        // phase 2: per-g argmax over this block's 256 p's (8 subs x 32 rows)
        {
            const int gl  = t & 31;
            const int g   = gbase + gl;
            const int r0  = (t >> 5) * 32;
            float bv = -0.5f;
            int   br = 0;
#pragma unroll 8
            for (int j = 0; j < 32; ++j) {
                float v = s_iou[r0 + j][gl];
                if (v > bv) { bv = v; br = r0 + j; }  // ascending r = smallest p
            }
            if (bv >= 0.0f) {
                unsigned long long key =
                    ((unsigned long long)__float_as_uint(bv) << 32) |
                    (unsigned long long)(0xFFFFFFFFu - (unsigned)(pbase + br));
                atomicMax(&s_red[g], key);
            }
        }
        __syncthreads();
    }

    if (t < G) {
        unsigned long long k = s_red[t];
        if (k) atomicMax(&packed[(size_t)b * G + t], k);
    }

    if (valid) {
        int lab = (bestIou < IOU_THR) ? 0 : s_lab[bestG];
        encode_store(out_loc, out_lab, b, p, s_gt[bestG], pr, lab);
    }
}

// Force-assign fixup: each gt overwrites its best prior; duplicate p resolved
// last-g-wins (matches jnp .at[].set scatter order).
__global__ __launch_bounds__(64) void k_fixup(
    const float* __restrict__ gt_boxes,
    const int*   __restrict__ gt_labels,
    const float* __restrict__ priors,
    const unsigned long long* __restrict__ packed,
    float* __restrict__ out_loc,
    float* __restrict__ out_lab)
{
    __shared__ int s_p[G];
    const int b = blockIdx.x;
    const int g = threadIdx.x;

    unsigned long long key = packed[(size_t)b * G + g];
    int p = (int)(0xFFFFFFFFu - (unsigned)(key & 0xFFFFFFFFull));
    s_p[g] = p;
    __syncthreads();

    bool win = true;
    for (int g2 = g + 1; g2 < G; ++g2)
        if (s_p[g2] == p) { win = false; break; }

    if (win) {
        float4 gb = *(const float4*)(gt_boxes + (size_t)(b * G + g) * 4);
        float4 pr = *(const float4*)(priors + (size_t)p * 4);
        int lab = gt_labels[b * G + g];   // forced: iou=2.0 >= thr, label kept
        encode_store(out_loc, out_lab, b, p, gb, pr, lab);
    }
}

extern "C" void kernel_launch(void* const* d_in, const int* in_sizes, int n_in,
                              void* d_out, int out_size, void* d_ws, size_t ws_size,
                              hipStream_t stream)
{
    const float* gt_boxes  = (const float*)d_in[0];
    const int*   gt_labels = (const int*)d_in[1];
    const float* priors    = (const float*)d_in[2];

    float* out_loc = (float*)d_out;                   // B*P*4 floats
    float* out_lab = out_loc + (size_t)B * P * 4;     // B*P floats
    unsigned long long* packed = (unsigned long long*)d_ws;  // B*G u64 (64 KB)

    k_zero<<<dim3((B * G + 255) / 256), 256, 0, stream>>>(packed);

    k_fused<<<dim3((P + 255) / 256, B), 256, 0, stream>>>(
        gt_boxes, gt_labels, priors, packed, out_loc, out_lab);

    k_fixup<<<dim3(B), 64, 0, stream>>>(
        gt_boxes, gt_labels, priors, packed, out_loc, out_lab);
}

// Round 3
// 77.200 us; speedup vs baseline: 1.7451x; 1.0774x over previous
//
#include <hip/hip_runtime.h>

static constexpr int B = 128;
static constexpr int G = 64;
static constexpr int P = 8732;
static constexpr float EPS = 1e-5f;
static constexpr float IOU_THR = 0.5f;

// Bitwise-numpy-identical IoU: no contraction, IEEE div, numpy association order:
//   lt=max, rb=min, hw=max(rb-lt,0), ov=hw0*hw1, den=((ga+pa)-ov)+eps, ov/den
__device__ __forceinline__ float iou_exact(
    float gx1, float gy1, float gx2, float gy2, float ga,
    float px1, float py1, float px2, float py2, float pa)
{
    float ltx = fmaxf(gx1, px1), lty = fmaxf(gy1, py1);
    float rbx = fminf(gx2, px2), rby = fminf(gy2, py2);
    float ow  = fmaxf(__fsub_rn(rbx, ltx), 0.0f);
    float oh  = fmaxf(__fsub_rn(rby, lty), 0.0f);
    float ov  = __fmul_rn(ow, oh);
    float den = __fadd_rn(__fsub_rn(__fadd_rn(ga, pa), ov), EPS);
    return __fdiv_rn(ov, den);
}

__device__ __forceinline__ void encode_store(
    float* out_loc, float* out_lab, int b, int p,
    float4 gb, float4 pr, int lab)
{
    float cx = (gb.x + gb.z) * 0.5f;
    float cy = (gb.y + gb.w) * 0.5f;
    float w  = gb.z - gb.x;
    float h  = gb.w - gb.y;
    float4 loc;
    loc.x = (cx - pr.x) / (pr.z * 0.1f);
    loc.y = (cy - pr.y) / (pr.w * 0.1f);
    loc.z = logf(w / pr.z) / 0.2f;
    loc.w = logf(h / pr.w) / 0.2f;
    *(float4*)(out_loc + (size_t)(b * P + p) * 4) = loc;
    out_lab[(size_t)b * P + p] = (float)lab;
}

// Zero the packed per-(b,g) reduction array each call (atomicMax is monotone;
// 0xAA poison would otherwise win forever).
__global__ __launch_bounds__(256) void k_zero(unsigned long long* __restrict__ packed)
{
    int i = blockIdx.x * 256 + threadIdx.x;
    if (i < B * G) packed[i] = 0ull;
}

// Fused single pass over all B*G*P IoUs, g processed in 4 quarters of 16 to
// keep LDS ~19.5 KB -> 8 blocks/CU (100% occupancy).
__global__ __launch_bounds__(256, 8) void k_fused(
    const float* __restrict__ gt_boxes,   // [B,G,4] corner
    const int*   __restrict__ gt_labels,  // [B,G]
    const float* __restrict__ priors,     // [P,4] center
    unsigned long long* __restrict__ packed,  // [B,G]
    float* __restrict__ out_loc,          // [B,P,4]
    float* __restrict__ out_lab)          // [B,P]
{
    __shared__ float4 s_gt[G];
    __shared__ float  s_ga[G];
    __shared__ int    s_lab[G];
    __shared__ unsigned long long s_red[G];
    __shared__ float  s_iou[256][17];     // stride 17: 2-way bank alias = free

    const int b = blockIdx.y;
    const int t = threadIdx.x;
    const int pbase = blockIdx.x * 256;
    const int p = pbase + t;
    const bool valid = p < P;

    if (t < G) {
        float4 gb = *(const float4*)(gt_boxes + (size_t)(b * G + t) * 4);
        s_gt[t]  = gb;
        s_ga[t]  = __fmul_rn(fmaxf(__fsub_rn(gb.z, gb.x), 0.0f),
                             fmaxf(__fsub_rn(gb.w, gb.y), 0.0f));
        s_lab[t] = gt_labels[b * G + t];
        s_red[t] = 0ull;
    }
    __syncthreads();

    // Invalid lanes get a degenerate zero prior -> iou == 0.0f exactly for all
    // g (rb-lt <= 0 -> ov=0; den>0). A zero iou at row r>=28 of the tail block
    // can never beat a valid row (strict > scan, ascending r), and key packing
    // ~p makes larger p lose ties globally. So no per-iteration predication.
    float4 pr = make_float4(0.f, 0.f, 0.f, 0.f);
    if (valid) pr = *(const float4*)(priors + (size_t)p * 4);
    float hw = __fmul_rn(pr.z, 0.5f), hh = __fmul_rn(pr.w, 0.5f);
    float px1 = __fsub_rn(pr.x, hw), py1 = __fsub_rn(pr.y, hh);
    float px2 = __fadd_rn(pr.x, hw), py2 = __fadd_rn(pr.y, hh);
    float pa  = __fmul_rn(fmaxf(__fsub_rn(px2, px1), 0.0f),
                          fmaxf(__fsub_rn(py2, py1), 0.0f));

    float bestIou = -1.0f;
    int   bestG   = 0;

    for (int q = 0; q < 4; ++q) {
        const int gbase = q * 16;
#pragma unroll
        for (int gi = 0; gi < 16; ++gi) {
            const int g = gbase + gi;
            float4 gb = s_gt[g];
            float iou = iou_exact(gb.x, gb.y, gb.z, gb.w, s_ga[g],
                                  px1, py1, px2, py2, pa);
            s_iou[t][gi] = iou;
            if (iou > bestIou) { bestIou = iou; bestG = g; }  // first-g tie-break
        }
        __syncthreads();

        // phase 2: per-g argmax over this block's 256 p's.
        // 16 threads per column (t&15 = col, t>>4 = row-group of 16).
        {
            const int c  = t & 15;
            const int r0 = (t >> 4) * 16;
            float bv = -0.5f;
            int   br = 0;
#pragma unroll
            for (int j = 0; j < 16; ++j) {
                float v = s_iou[r0 + j][c];
                if (v > bv) { bv = v; br = r0 + j; }  // ascending r = smallest p
            }
            unsigned long long key =
                ((unsigned long long)__float_as_uint(bv) << 32) |
                (unsigned long long)(0xFFFFFFFFu - (unsigned)(pbase + br));
            atomicMax(&s_red[gbase + c], key);
        }
        __syncthreads();
    }

    if (t < G) {
        unsigned long long k = s_red[t];
        atomicMax(&packed[(size_t)b * G + t], k);
    }

    if (valid) {
        int lab = (bestIou < IOU_THR) ? 0 : s_lab[bestG];
        encode_store(out_loc, out_lab, b, p, s_gt[bestG], pr, lab);
    }
}

// Force-assign fixup: each gt overwrites its best prior; duplicate p resolved
// last-g-wins (matches jnp .at[].set scatter order).
__global__ __launch_bounds__(64) void k_fixup(
    const float* __restrict__ gt_boxes,
    const int*   __restrict__ gt_labels,
    const float* __restrict__ priors,
    const unsigned long long* __restrict__ packed,
    float* __restrict__ out_loc,
    float* __restrict__ out_lab)
{
    __shared__ int s_p[G];
    const int b = blockIdx.x;
    const int g = threadIdx.x;

    unsigned long long key = packed[(size_t)b * G + g];
    int p = (int)(0xFFFFFFFFu - (unsigned)(key & 0xFFFFFFFFull));
    s_p[g] = p;
    __syncthreads();

    bool win = true;
    for (int g2 = g + 1; g2 < G; ++g2)
        if (s_p[g2] == p) { win = false; break; }

    if (win) {
        float4 gb = *(const float4*)(gt_boxes + (size_t)(b * G + g) * 4);
        float4 pr = *(const float4*)(priors + (size_t)p * 4);
        int lab = gt_labels[b * G + g];   // forced: iou=2.0 >= thr, label kept
        encode_store(out_loc, out_lab, b, p, gb, pr, lab);
    }
}

extern "C" void kernel_launch(void* const* d_in, const int* in_sizes, int n_in,
                              void* d_out, int out_size, void* d_ws, size_t ws_size,
                              hipStream_t stream)
{
    const float* gt_boxes  = (const float*)d_in[0];
    const int*   gt_labels = (const int*)d_in[1];
    const float* priors    = (const float*)d_in[2];

    float* out_loc = (float*)d_out;                   // B*P*4 floats
    float* out_lab = out_loc + (size_t)B * P * 4;     // B*P floats
    unsigned long long* packed = (unsigned long long*)d_ws;  // B*G u64 (64 KB)

    k_zero<<<dim3((B * G + 255) / 256), 256, 0, stream>>>(packed);

    k_fused<<<dim3((P + 255) / 256, B), 256, 0, stream>>>(
        gt_boxes, gt_labels, priors, packed, out_loc, out_lab);

    k_fixup<<<dim3(B), 64, 0, stream>>>(
        gt_boxes, gt_labels, priors, packed, out_loc, out_lab);
}